// Round 19
// baseline (161.158 us; speedup 1.0000x reference)
//
#include <hip/hip_runtime.h>

#define TT 256
#define BB 512
#define DD 128
#define HH 50
#define KK 5
#define AA 4
#define NROW 131072
#define KQS 260          // kqg row stride

#define R50(X) X(0) X(1) X(2) X(3) X(4) X(5) X(6) X(7) X(8) X(9) \
  X(10) X(11) X(12) X(13) X(14) X(15) X(16) X(17) X(18) X(19) \
  X(20) X(21) X(22) X(23) X(24) X(25) X(26) X(27) X(28) X(29) \
  X(30) X(31) X(32) X(33) X(34) X(35) X(36) X(37) X(38) X(39) \
  X(40) X(41) X(42) X(43) X(44) X(45) X(46) X(47) X(48) X(49)

typedef _Float16 half4 __attribute__((ext_vector_type(4)));
typedef float f32x4 __attribute__((ext_vector_type(4)));

// ---------------- K0: weight prep ----------------
__global__ void k0_prep(const float* __restrict__ W_in,
                        const float* __restrict__ W_ctx,
                        const float* __restrict__ W_key,
                        const float* __restrict__ W_q,
                        const float* __restrict__ b_key,
                        const float* __restrict__ b_q,
                        float* __restrict__ WHT,
                        float* __restrict__ WK2T, float* __restrict__ bias2) {
  int i = blockIdx.x * 256 + threadIdx.x;
  if (i < HH * 52) {
    int j = i / 52, h = i % 52;
    WHT[i] = (h < HH) ? W_ctx[h * (2 * HH) + HH + j] : 0.f;
  }
  if (i < HH * 64) {
    int j = i >> 6, l = i & 63;
    float v = 0.f;
    if (l < HH) v = W_ctx[l * (2 * HH) + j];
    else if (l < HH + KK) v = W_key[(l - HH) * HH + j];
    else if (l < HH + 2 * KK) v = W_q[(l - HH - KK) * HH + j];
    WK2T[i] = v;
  }
  if (i < 64) {
    float bv = 0.f;
    if (i >= HH && i < HH + KK) bv = b_key[i - HH];
    else if (i >= HH + KK && i < HH + 2 * KK) bv = b_q[i - HH - KK];
    bias2[i] = bv;
  }
}

// ---------------- K1 (MFMA, fused): g = relu(x@W_in^T+b_in)@Wh^T + b_ctx ---
// As R18 (verified) but g stored f16, stride 64, slots 50-63 zeroed.
__global__ __launch_bounds__(256, 2) void k1_mfma(
    const float* __restrict__ x, const float* __restrict__ W_in,
    const float* __restrict__ WHT, const float* __restrict__ b_in,
    const float* __restrict__ b_ctx, _Float16* __restrict__ gh) {
  const int lane = threadIdx.x & 63;
  const int wave = threadIdx.x >> 6;
  const int lrow = lane & 15, lgrp = lane >> 4;

#define WA1D(m, kk)                                                     \
  half4 wa1_##m##_##kk;                                                 \
  {                                                                     \
    const int hh = 16 * (m) + lrow;                                     \
    const int j0 = 16 * (kk) + 4 * lgrp;                                \
    const bool v = (hh < HH);                                           \
    const float* p = W_in + (size_t)(v ? hh : 0) * DD + j0;             \
    wa1_##m##_##kk[0] = (_Float16)(v ? p[0] : 0.f);                     \
    wa1_##m##_##kk[1] = (_Float16)(v ? p[1] : 0.f);                     \
    wa1_##m##_##kk[2] = (_Float16)(v ? p[2] : 0.f);                     \
    wa1_##m##_##kk[3] = (_Float16)(v ? p[3] : 0.f);                     \
  }
  WA1D(0, 0) WA1D(0, 1) WA1D(0, 2) WA1D(0, 3)
  WA1D(0, 4) WA1D(0, 5) WA1D(0, 6) WA1D(0, 7)
  WA1D(1, 0) WA1D(1, 1) WA1D(1, 2) WA1D(1, 3)
  WA1D(1, 4) WA1D(1, 5) WA1D(1, 6) WA1D(1, 7)
  WA1D(2, 0) WA1D(2, 1) WA1D(2, 2) WA1D(2, 3)
  WA1D(2, 4) WA1D(2, 5) WA1D(2, 6) WA1D(2, 7)
  WA1D(3, 0) WA1D(3, 1) WA1D(3, 2) WA1D(3, 3)
  WA1D(3, 4) WA1D(3, 5) WA1D(3, 6) WA1D(3, 7)

#define WA2D(m, kk)                                                     \
  half4 wa2_##m##_##kk;                                                 \
  {                                                                     \
    const int gg = 16 * (m) + lrow;                                     \
    const int h0 = 16 * (kk) + 4 * lgrp;                                \
    wa2_##m##_##kk[0] = (_Float16)((gg < HH && h0 + 0 < HH) ? WHT[(h0 + 0) * 52 + gg] : 0.f); \
    wa2_##m##_##kk[1] = (_Float16)((gg < HH && h0 + 1 < HH) ? WHT[(h0 + 1) * 52 + gg] : 0.f); \
    wa2_##m##_##kk[2] = (_Float16)((gg < HH && h0 + 2 < HH) ? WHT[(h0 + 2) * 52 + gg] : 0.f); \
    wa2_##m##_##kk[3] = (_Float16)((gg < HH && h0 + 3 < HH) ? WHT[(h0 + 3) * 52 + gg] : 0.f); \
  }
  WA2D(0, 0) WA2D(0, 1) WA2D(0, 2) WA2D(0, 3)
  WA2D(1, 0) WA2D(1, 1) WA2D(1, 2) WA2D(1, 3)
  WA2D(2, 0) WA2D(2, 1) WA2D(2, 2) WA2D(2, 3)
  WA2D(3, 0) WA2D(3, 1) WA2D(3, 2) WA2D(3, 3)

#define BDEF(m, r)                                                      \
  const float bin_##m##_##r =                                           \
      (16 * (m) + 4 * lgrp + (r) < HH) ? b_in[16 * (m) + 4 * lgrp + (r)] : 0.f; \
  const float bct_##m##_##r =                                           \
      (16 * (m) + 4 * lgrp + (r) < HH) ? b_ctx[16 * (m) + 4 * lgrp + (r)] : 0.f;
  BDEF(0, 0) BDEF(0, 1) BDEF(0, 2) BDEF(0, 3)
  BDEF(1, 0) BDEF(1, 1) BDEF(1, 2) BDEF(1, 3)
  BDEF(2, 0) BDEF(2, 1) BDEF(2, 2) BDEF(2, 3)
  BDEF(3, 0) BDEF(3, 1) BDEF(3, 2) BDEF(3, 3)

  const f32x4 zf = {0.f, 0.f, 0.f, 0.f};

#pragma unroll 1
  for (int it = 0; it < 4; ++it) {
    const int tile = (blockIdx.x * 4 + wave) * 4 + it;
    const int row = tile * 16 + lrow;
    const float* __restrict__ xr = x + (size_t)row * DD + 4 * lgrp;

#define XLD(kk)                                                         \
  half4 xb##kk;                                                         \
  {                                                                     \
    const float4 xv = *reinterpret_cast<const float4*>(xr + 16 * kk);   \
    xb##kk[0] = (_Float16)xv.x;                                         \
    xb##kk[1] = (_Float16)xv.y;                                         \
    xb##kk[2] = (_Float16)xv.z;                                         \
    xb##kk[3] = (_Float16)xv.w;                                         \
  }
    XLD(0) XLD(1) XLD(2) XLD(3) XLD(4) XLD(5) XLD(6) XLD(7)

    f32x4 d10 = zf, d11 = zf, d12 = zf, d13 = zf;
#define MM1(kk)                                                              \
  d10 = __builtin_amdgcn_mfma_f32_16x16x16f16(wa1_0_##kk, xb##kk, d10, 0, 0, 0); \
  d11 = __builtin_amdgcn_mfma_f32_16x16x16f16(wa1_1_##kk, xb##kk, d11, 0, 0, 0); \
  d12 = __builtin_amdgcn_mfma_f32_16x16x16f16(wa1_2_##kk, xb##kk, d12, 0, 0, 0); \
  d13 = __builtin_amdgcn_mfma_f32_16x16x16f16(wa1_3_##kk, xb##kk, d13, 0, 0, 0);
    MM1(0) MM1(1) MM1(2) MM1(3) MM1(4) MM1(5) MM1(6) MM1(7)

#define HBD(k)                                                    \
  half4 hb##k;                                                    \
  hb##k[0] = (_Float16)fmaxf(d1##k[0] + bin_##k##_0, 0.f);        \
  hb##k[1] = (_Float16)fmaxf(d1##k[1] + bin_##k##_1, 0.f);        \
  hb##k[2] = (_Float16)fmaxf(d1##k[2] + bin_##k##_2, 0.f);        \
  hb##k[3] = (_Float16)fmaxf(d1##k[3] + bin_##k##_3, 0.f);
    HBD(0) HBD(1) HBD(2) HBD(3)

    f32x4 d20 = zf, d21 = zf, d22 = zf, d23 = zf;
#define MM2(kk)                                                              \
  d20 = __builtin_amdgcn_mfma_f32_16x16x16f16(wa2_0_##kk, hb##kk, d20, 0, 0, 0); \
  d21 = __builtin_amdgcn_mfma_f32_16x16x16f16(wa2_1_##kk, hb##kk, d21, 0, 0, 0); \
  d22 = __builtin_amdgcn_mfma_f32_16x16x16f16(wa2_2_##kk, hb##kk, d22, 0, 0, 0); \
  d23 = __builtin_amdgcn_mfma_f32_16x16x16f16(wa2_3_##kk, hb##kk, d23, 0, 0, 0);
    MM2(0) MM2(1) MM2(2) MM2(3)

    // store g^T f16 -> gh[(b*TT + t)*64 + gg]; slots 50-63 zeroed
    _Float16* __restrict__ gr =
        gh + ((size_t)(row & (BB - 1)) * TT + (row >> 9)) * 64;
#define GST4(off, D, B0, B1, B2, B3)                          \
  {                                                           \
    half4 v;                                                  \
    v[0] = (_Float16)(D[0] + B0);                             \
    v[1] = (_Float16)(D[1] + B1);                             \
    v[2] = (_Float16)(D[2] + B2);                             \
    v[3] = (_Float16)(D[3] + B3);                             \
    *reinterpret_cast<half4*>(gr + (off) + 4 * lgrp) = v;     \
  }
    GST4(0, d20, bct_0_0, bct_0_1, bct_0_2, bct_0_3)
    GST4(16, d21, bct_1_0, bct_1_1, bct_1_2, bct_1_3)
    GST4(32, d22, bct_2_0, bct_2_1, bct_2_2, bct_2_3)
    {  // slots 48-63: gg 48,49 valid (lgrp 0); everything else 0
      half4 v;
      v[0] = (_Float16)((lgrp == 0) ? d23[0] + bct_3_0 : 0.f);
      v[1] = (_Float16)((lgrp == 0) ? d23[1] + bct_3_1 : 0.f);
      v[2] = (_Float16)0.f;
      v[3] = (_Float16)0.f;
      *reinterpret_cast<half4*>(gr + 48 + 4 * lgrp) = v;
    }
  }
}

// ---------------- K2: per-batch recurrence (512 blocks x 1 wave) -----------
// Scalar core; ALL per-body ops unconditional (no exec-mask toggles):
// ctxg64 stride 64 (junk at h>=50 never read), c_lds write unconditional
// (slots 50/51 multiply by wz=0; 52-63 never read), g padded with zeros.
// 8-deep named gq prefetch; kq float4-batched egress.
__global__ __launch_bounds__(64) void k2_rec(
    const _Float16* __restrict__ gh, const float* __restrict__ WK2T,
    const float* __restrict__ bias2, const float* __restrict__ first_context,
    float* __restrict__ ctxg64, float* __restrict__ kqg) {
  __shared__ __align__(16) float c_lds[64];
  const int b = blockIdx.x;
  const int lane = threadIdx.x;

#define WDECL(j)                            \
  float w##j = WK2T[(j) * 64 + lane];       \
  asm volatile("" : "+v"(w##j));
  R50(WDECL)
  const float wz = 0.f;
  const float bias = bias2[lane];

  const float c0v = (lane < HH) ? first_context[lane] : 0.f;
  c_lds[lane] = c0v;
  ctxg64[((size_t)b * 257 + 0) * 64 + lane] = c0v;

  const _Float16* __restrict__ gbp = gh + (size_t)b * TT * 64 + lane;
  float gq0 = (float)gbp[0 * 64];
  float gq1 = (float)gbp[1 * 64];
  float gq2 = (float)gbp[2 * 64];
  float gq3 = (float)gbp[3 * 64];
  float gq4 = (float)gbp[4 * 64];
  float gq5 = (float)gbp[5 * 64];
  float gq6 = (float)gbp[6 * 64];
  float gq7 = (float)gbp[7 * 64];

  float* __restrict__ ctp = ctxg64 + (size_t)b * 257 * 64 + lane;
  const bool iskq = (lane >= HH && lane < HH + 2 * KK);
  float* __restrict__ kqrow =
      kqg + ((size_t)b * 10 + (iskq ? lane - HH : 0)) * KQS;

#define KQ(J, wa, wb, wc, wd)                                            \
  {                                                                      \
    const float4 cq = *reinterpret_cast<const float4*>(&c_lds[J]);       \
    acc0 = fmaf(wa, cq.x, acc0);                                         \
    acc1 = fmaf(wb, cq.y, acc1);                                         \
    acc2 = fmaf(wc, cq.z, acc2);                                         \
    acc3 = fmaf(wd, cq.w, acc3);                                         \
  }
#define DOT50R                                                           \
  float acc0 = 0.f, acc1 = 0.f, acc2 = 0.f, acc3 = 0.f;                  \
  KQ(0, w0, w1, w2, w3) KQ(4, w4, w5, w6, w7)                            \
  KQ(8, w8, w9, w10, w11) KQ(12, w12, w13, w14, w15)                     \
  KQ(16, w16, w17, w18, w19) KQ(20, w20, w21, w22, w23)                  \
  KQ(24, w24, w25, w26, w27) KQ(28, w28, w29, w30, w31)                  \
  KQ(32, w32, w33, w34, w35) KQ(36, w36, w37, w38, w39)                  \
  KQ(40, w40, w41, w42, w43) KQ(44, w44, w45, w46, w47)                  \
  KQ(48, w48, w49, wz, wz)                                               \
  const float acc = (acc0 + acc1) + (acc2 + acc3);

#define BODY(RR, GQ)                                                     \
  {                                                                      \
    const int t = tg8 + RR;                                              \
    DOT50R                                                               \
    kqa##RR = acc + bias;                                                \
    const float cn = fmaxf(acc + GQ, 0.f);                               \
    GQ = (float)gbp[(size_t)min(t + 8, TT - 1) * 64];                    \
    ctp[(size_t)(t + 1) * 64] = cn;                                      \
    c_lds[lane] = cn;  /* in-wave DS order: visible next body */         \
  }

#pragma unroll 1
  for (int tg8 = 0; tg8 < TT; tg8 += 8) {
    float kqa0, kqa1, kqa2, kqa3, kqa4, kqa5, kqa6, kqa7;
    BODY(0, gq0) BODY(1, gq1) BODY(2, gq2) BODY(3, gq3)
    BODY(4, gq4) BODY(5, gq5) BODY(6, gq6) BODY(7, gq7)
    if (iskq) {
      *reinterpret_cast<float4*>(kqrow + tg8) =
          make_float4(kqa0, kqa1, kqa2, kqa3);
      *reinterpret_cast<float4*>(kqrow + tg8 + 4) =
          make_float4(kqa4, kqa5, kqa6, kqa7);
    }
  }

  {  // tail: key/q of c_TT at index TT
    DOT50R
    if (iskq) kqrow[TT] = acc + bias;
  }
}

// ---------------- K3: MFMA flash attention (R17 verified; ctx stride 64) ---
__global__ __launch_bounds__(256, 4) void k3_attn(
    const float* __restrict__ ctxg64, const float* __restrict__ kqg,
    const float* __restrict__ W_act, const float* __restrict__ b_act,
    float* __restrict__ out) {
  __shared__ __align__(16) float ct[64 * 66];
  __shared__ __align__(16) float k_l[16 * 68];  // rows 5-15 hard-zeroed
  __shared__ __align__(16) float o_l[64 * 66];
  __shared__ float su_l[64];

  const int tid = threadIdx.x;
  const int bid = blockIdx.x;
  const int chunk = 3 - (bid >> 9);
  const int b = bid & 511;
  const int tbase = chunk * 64;
  const int nst = min(tbase + 66, 257);
  const int ntiles = (nst + 63) >> 6;
  const int wave = tid >> 6;
  const int lane = tid & 63;
  const int lrow = lane & 15;
  const int lgrp = lane >> 4;
  const int tw = tbase + wave * 16;

  for (int i = tid; i < 11 * 68; i += 256) k_l[5 * 68 + i] = 0.f;

  half4 qf;
#pragma unroll
  for (int i = 0; i < 4; ++i) {
    const int k = 4 * lgrp + i;
    qf[i] = (_Float16)((k < KK)
                           ? kqg[((size_t)b * 10 + 5 + k) * KQS + tw + lrow + 1]
                           : 0.f);
  }

  const f32x4 zf = {0.f, 0.f, 0.f, 0.f};
  f32x4 acc0 = zf, acc1 = zf, acc2 = zf, acc3 = zf;
  float su = 0.f;

#pragma unroll 1
  for (int tile = 0; tile < ntiles; ++tile) {
    __syncthreads();
    {
      const int r = tid >> 2;
      const int c0 = (tid & 3) * 16;
      const int srow = tile * 64 + r;
      const float* src = ctxg64 + ((size_t)b * 257 + srow) * 64;
      const bool sv = (srow < nst);
#pragma unroll
      for (int u = 0; u < 8; ++u) {
        const int c = c0 + u * 2;
        float2 v = make_float2(0.f, 0.f);
        if (sv && c < HH) v = *reinterpret_cast<const float2*>(src + c);
        *reinterpret_cast<float2*>(&ct[r * 66 + c]) = v;
      }
    }
    {
      for (int i = tid; i < KK * 64; i += 256) {
        const int k = i >> 6, sl = i & 63;
        const int s = tile * 64 + sl;
        k_l[k * 68 + sl] =
            (s <= TT) ? kqg[((size_t)b * 10 + k) * KQS + s] : 0.f;
      }
    }
    __syncthreads();

    if (tile * 64 <= tw + 16) {
#pragma unroll 1
      for (int su16 = 0; su16 < 4; ++su16) {
        const int sb = tile * 64 + su16 * 16;
        if (sb > tw + 16) break;

        half4 kf;
#pragma unroll
        for (int i = 0; i < 4; ++i)
          kf[i] = (_Float16)k_l[(4 * lgrp + i) * 68 + su16 * 16 + lrow];

        const f32x4 sc =
            __builtin_amdgcn_mfma_f32_16x16x16f16(kf, qf, zf, 0, 0, 0);

        half4 pa;
#pragma unroll
        for (int r = 0; r < 4; ++r) {
          const int s = sb + 4 * lgrp + r;
          const float p = (s <= tw + lrow + 1) ? __expf(sc[r]) : 0.f;
          su += p;
          pa[r] = (_Float16)p;
        }

        const int vbase = su16 * 16 + 4 * lgrp;
#define PVHT(HT, ACC)                                                     \
  {                                                                       \
    half4 vf;                                                             \
    vf[0] = (_Float16)ct[(vbase + 0) * 66 + lrow + 16 * HT];              \
    vf[1] = (_Float16)ct[(vbase + 1) * 66 + lrow + 16 * HT];              \
    vf[2] = (_Float16)ct[(vbase + 2) * 66 + lrow + 16 * HT];              \
    vf[3] = (_Float16)ct[(vbase + 3) * 66 + lrow + 16 * HT];              \
    ACC = __builtin_amdgcn_mfma_f32_16x16x16f16(pa, vf, ACC, 0, 0, 0);    \
  }
        PVHT(0, acc0) PVHT(1, acc1) PVHT(2, acc2) PVHT(3, acc3)
      }
    }
  }

  su += __shfl_xor(su, 16, 64);
  su += __shfl_xor(su, 32, 64);
  if (lane < 16) su_l[wave * 16 + lane] = su;

#pragma unroll
  for (int r = 0; r < 4; ++r) {
    const int trow = wave * 16 + 4 * lgrp + r;
    o_l[trow * 66 + lrow + 0] = acc0[r];
    o_l[trow * 66 + lrow + 16] = acc1[r];
    o_l[trow * 66 + lrow + 32] = acc2[r];
    o_l[trow * 66 + lrow + 48] = acc3[r];
  }
  __syncthreads();

  {
    const int tl = tid >> 2;
    const int a = tid & 3;
    const float inv = 1.f / su_l[tl];
    const float* orow = &o_l[tl * 66];
    const float* wrow = W_act + a * HH;
    float s0 = 0.f, s1 = 0.f;
#pragma unroll
    for (int h = 0; h < HH; h += 2) {
      s0 = fmaf(orow[h], wrow[h], s0);
      s1 = fmaf(orow[h + 1], wrow[h + 1], s1);
    }
    out[((size_t)(tbase + tl) * BB + b) * AA + a] =
        fmaf(s0 + s1, inv, b_act[a]);
  }
}

extern "C" void kernel_launch(void* const* d_in, const int* in_sizes, int n_in,
                              void* d_out, int out_size, void* d_ws,
                              size_t ws_size, hipStream_t stream) {
  const float* x = (const float*)d_in[0];
  const float* W_in = (const float*)d_in[1];
  const float* b_in = (const float*)d_in[2];
  const float* W_ctx = (const float*)d_in[3];
  const float* b_ctx = (const float*)d_in[4];
  const float* W_key = (const float*)d_in[5];
  const float* b_key = (const float*)d_in[6];
  const float* W_q = (const float*)d_in[7];
  const float* b_q = (const float*)d_in[8];
  const float* fc = (const float*)d_in[9];
  const float* W_act = (const float*)d_in[10];
  const float* b_act = (const float*)d_in[11];
  float* out = (float*)d_out;
  float* ws = (float*)d_ws;

  float* WHT = ws;                                  // 50*52
  float* WK2T = ws + 4096;                          // 50*64
  float* bias2 = ws + 8128;                         // 64
  _Float16* gh = (_Float16*)(ws + 8192);            // 131072*64 f16 (16.8MB)
  float* ctxg64 = ws + 8192 + 4194304;              // 512*257*64 (33.7MB)
  float* kqg = ctxg64 + (size_t)BB * 257 * 64;      // 512*10*260 (5.3MB)
  // total ~56 MB

  hipLaunchKernelGGL(k0_prep, dim3(26), dim3(256), 0, stream, W_in, W_ctx,
                     W_key, W_q, b_key, b_q, WHT, WK2T, bias2);
  hipLaunchKernelGGL(k1_mfma, dim3(512), dim3(256), 0, stream, x, W_in, WHT,
                     b_in, b_ctx, gh);
  hipLaunchKernelGGL(k2_rec, dim3(512), dim3(64), 0, stream, gh, WK2T, bias2,
                     fc, ctxg64, kqg);
  hipLaunchKernelGGL(k3_attn, dim3(2048), dim3(256), 0, stream, ctxg64, kqg,
                     W_act, b_act, out);
}